// Round 2
// 389.919 us; speedup vs baseline: 1.0116x; 1.0116x over previous
//
#include <hip/hip_runtime.h>

#define ED 128   // embedding dim (== RD)

// v2b: one 32-lane half-wave per sample (2 samples per wave64). Each lane owns
// 4 consecutive floats (16B/lane -> 512B per row per group, fully coalesced).
// Butterfly reduction is 5 steps at width=32 (no lane^32 cross-half exchange).
// Uses clang ext_vector_type instead of HIP float4 so that
// __builtin_nontemporal_load/store accepts the pointer (HIP float4 is a
// struct; the builtin requires a true vector type).
//
// Math (collapsed from the reference; eye = 128x128 identity):
//   h_out  = rp_hat * dot(hp_hat, hv_hat) + hv_hat
//   rv_out = rv_hat
//   t_out  = rp_hat * dot(tp_hat, tv_hat) + tv_hat
// where x_hat = x * sc_x, sc_x = (||x|| > 1) ? 1/(||x||+1e-7) : 1
// and dot(x_hat, y_hat) = sc_x * sc_y * dot(x, y).

typedef float f32x4 __attribute__((ext_vector_type(4)));

__global__ __launch_bounds__(256) void transd_kernel(
    const float* __restrict__ ent,   // [ENT, 128]
    const float* __restrict__ entp,  // [ENT, 128]
    const float* __restrict__ rel,   // [REL, 128]
    const float* __restrict__ relp,  // [REL, 128]
    const int* __restrict__ h,
    const int* __restrict__ r,
    const int* __restrict__ t,
    float* __restrict__ out,         // [3, B, 128] concat: h_out, rv, t_out
    int B)
{
    const int sample = (blockIdx.x * blockDim.x + threadIdx.x) >> 5;
    const int lane   = threadIdx.x & 31;
    if (sample >= B) return;

    const int hi = h[sample];
    const int ri = r[sample];
    const int ti = t[sample];

    // Entity tables (2 x 256 MB) are randomly gathered with ~no reuse inside
    // one launch -> nontemporal, don't thrash L2/L3. Relation tables (512 KB,
    // B=8192 draws over 1000 rows) are hot -> normal cached loads.
    const f32x4* hp_p = (const f32x4*)(entp + (size_t)hi * ED) + lane;
    const f32x4* hv_p = (const f32x4*)(ent  + (size_t)hi * ED) + lane;
    const f32x4* tp_p = (const f32x4*)(entp + (size_t)ti * ED) + lane;
    const f32x4* tv_p = (const f32x4*)(ent  + (size_t)ti * ED) + lane;

    const f32x4 hp = __builtin_nontemporal_load(hp_p);
    const f32x4 hv = __builtin_nontemporal_load(hv_p);
    const f32x4 tp = __builtin_nontemporal_load(tp_p);
    const f32x4 tv = __builtin_nontemporal_load(tv_p);
    const f32x4 rp = ((const f32x4*)(relp + (size_t)ri * ED))[lane];
    const f32x4 rv = ((const f32x4*)(rel  + (size_t)ri * ED))[lane];

    // per-lane partial sums: 6 squared norms + 2 raw dots
    float s_hp = hp.x*hp.x + hp.y*hp.y + hp.z*hp.z + hp.w*hp.w;
    float s_hv = hv.x*hv.x + hv.y*hv.y + hv.z*hv.z + hv.w*hv.w;
    float s_rp = rp.x*rp.x + rp.y*rp.y + rp.z*rp.z + rp.w*rp.w;
    float s_rv = rv.x*rv.x + rv.y*rv.y + rv.z*rv.z + rv.w*rv.w;
    float s_tp = tp.x*tp.x + tp.y*tp.y + tp.z*tp.z + tp.w*tp.w;
    float s_tv = tv.x*tv.x + tv.y*tv.y + tv.z*tv.z + tv.w*tv.w;
    float d_h  = hp.x*hv.x + hp.y*hv.y + hp.z*hv.z + hp.w*hv.w;
    float d_t  = tp.x*tv.x + tp.y*tv.y + tp.z*tv.z + tp.w*tv.w;

    // 32-lane butterfly (width=32 keeps the two samples in a wave separate)
    #pragma unroll
    for (int off = 16; off >= 1; off >>= 1) {
        s_hp += __shfl_xor(s_hp, off, 32);
        s_hv += __shfl_xor(s_hv, off, 32);
        s_rp += __shfl_xor(s_rp, off, 32);
        s_rv += __shfl_xor(s_rv, off, 32);
        s_tp += __shfl_xor(s_tp, off, 32);
        s_tv += __shfl_xor(s_tv, off, 32);
        d_h  += __shfl_xor(d_h,  off, 32);
        d_t  += __shfl_xor(d_t,  off, 32);
    }

    auto renorm_scale = [](float s2) -> float {
        float n = sqrtf(s2);
        return (n > 1.0f) ? (1.0f / (n + 1e-7f)) : 1.0f;
    };

    const float sc_hv = renorm_scale(s_hv);
    const float sc_rv = renorm_scale(s_rv);
    const float sc_tv = renorm_scale(s_tv);
    const float dh  = d_h * renorm_scale(s_hp) * sc_hv;  // dot(hp_hat, hv_hat)
    const float dt  = d_t * renorm_scale(s_tp) * sc_tv;  // dot(tp_hat, tv_hat)
    const float arp = renorm_scale(s_rp);                // rp_hat = rp * arp

    f32x4 h_out, rv_out, t_out;
    h_out  = rp * (arp * dh) + hv * sc_hv;
    rv_out = rv * sc_rv;
    t_out  = rp * (arp * dt) + tv * sc_tv;

    // outputs are never re-read by us -> nontemporal stores
    const size_t row  = (size_t)sample * 32 + lane;     // in f32x4 units
    const size_t sect = (size_t)B * 32;                 // one output section
    f32x4* o = (f32x4*)out;
    __builtin_nontemporal_store(h_out,  o + row);
    __builtin_nontemporal_store(rv_out, o + sect + row);
    __builtin_nontemporal_store(t_out,  o + 2 * sect + row);
}

extern "C" void kernel_launch(void* const* d_in, const int* in_sizes, int n_in,
                              void* d_out, int out_size, void* d_ws, size_t ws_size,
                              hipStream_t stream) {
    const float* ent  = (const float*)d_in[0];
    const float* entp = (const float*)d_in[1];
    const float* rel  = (const float*)d_in[2];
    const float* relp = (const float*)d_in[3];
    const int*   h    = (const int*)d_in[4];
    const int*   r    = (const int*)d_in[5];
    const int*   t    = (const int*)d_in[6];
    float* out = (float*)d_out;

    const int B = in_sizes[4];           // 8192
    const int samples_per_block = 8;     // 256 threads = 8 x 32-lane groups
    const int grid = (B + samples_per_block - 1) / samples_per_block;
    transd_kernel<<<grid, 256, 0, stream>>>(ent, entp, rel, relp, h, r, t, out, B);
}